// Round 8
// baseline (11183.533 us; speedup 1.0000x reference)
//
#include <hip/hip_runtime.h>
#include <hip/hip_fp16.h>

typedef __attribute__((ext_vector_type(8))) short s16x8;
typedef __attribute__((ext_vector_type(8))) _Float16 f16x8;
typedef __attribute__((ext_vector_type(4))) float f32x4;

// ---------------------------------------------------------------------------
// Dequant 8 int4-in-int32 -> 8 fp16 via bit-trick + pk_fma.
// f16(64+q) = 0x5400 | (q<<4);  w = b*s - (64+z)*s
// ---------------------------------------------------------------------------
__device__ __forceinline__ s16x8 dq_compute(int4 q0, int4 q1, float s, float z) {
  __half hs = __float2half(s);
  __half2 s2 = __halves2half2(hs, hs);
  __half hc = __float2half(-(64.f + z) * s);
  __half2 c2 = __halves2half2(hc, hc);
  uint32_t b0 = 0x54005400u + ((uint32_t)q0.x << 4) + ((uint32_t)q0.y << 20);
  uint32_t b1 = 0x54005400u + ((uint32_t)q0.z << 4) + ((uint32_t)q0.w << 20);
  uint32_t b2 = 0x54005400u + ((uint32_t)q1.x << 4) + ((uint32_t)q1.y << 20);
  uint32_t b3 = 0x54005400u + ((uint32_t)q1.z << 4) + ((uint32_t)q1.w << 20);
  union { s16x8 v; __half2 h2[4]; } w;
  w.h2[0] = __hfma2(*(__half2*)&b0, s2, c2);
  w.h2[1] = __hfma2(*(__half2*)&b1, s2, c2);
  w.h2[2] = __hfma2(*(__half2*)&b2, s2, c2);
  w.h2[3] = __hfma2(*(__half2*)&b3, s2, c2);
  return w.v;
}

// bijective XCD swizzle (m204): consecutive logical ids land on the same XCD.
__device__ __forceinline__ int xcd_swz(int w0, int nwg) {
  const int q = nwg >> 3, r = nwg & 7;
  const int xcd = w0 & 7, idx = w0 >> 3;
  const int base = (xcd < r) ? xcd * (q + 1) : r * (q + 1) + (xcd - r) * q;
  return base + idx;
}

// ---------------------------------------------------------------------------
// gate/up GEMM over one I-panel:  P = X @ Wq^T  (dequant inline).
// EPI=0 (gate): Pan = fp16(acc).  EPI=1 (up): Pan = silu(Pan) * acc  [in-place]
// A: fp32 X loaded to regs, cvt->fp16, swizzled ds_write (0-conflict layout).
// Tile 128x128x64, 4 waves, 32 KB LDS, 4 blocks/CU.
// ---------------------------------------------------------------------------
template <int EPI>
__global__ __launch_bounds__(256, 4)
void qgemm_x_kernel(const float* __restrict__ X,
                    const int* __restrict__ Q,
                    const float* __restrict__ S, const float* __restrict__ Z,
                    __half* __restrict__ Pan,
                    int i0, int Iw, int nbB) {
  constexpr int H = 4096, G = 32;
  const int wg = xcd_swz(blockIdx.x, gridDim.x);
  const int nb = wg % nbB;   // nb fastest: co-resident blocks share the X tile
  const int mb = wg / nbB;
  const int m0 = mb * 128;
  const int n0g = i0 + nb * 128;
  const int tid = threadIdx.x;
  const int lane = tid & 63;
  const int wave = tid >> 6;
  const int wm = (wave >> 1) * 64, wn = (wave & 1) * 64;
  const int l15 = lane & 15, lq = lane >> 4;
  const int rsw = (l15 & 7) << 3;

  __shared__ __half As[128][64];   // 16 KB
  __shared__ __half Bs[128][64];   // 16 KB

  f32x4 acc[4][4];
#pragma unroll
  for (int i = 0; i < 4; ++i)
#pragma unroll
    for (int j = 0; j < 4; ++j) acc[i][j] = {0.f, 0.f, 0.f, 0.f};

  // per-thread staging: one row, 32 cols (two 16-col halves) for A and B
  const int arow = tid >> 1;
  const int acol0 = (tid & 1) * 32;
  const int asw = (arow & 7) << 3;

  for (int k0 = 0; k0 < H; k0 += 64) {
    const int gidx = k0 >> 7;
    __syncthreads();
    // ---- stage A: fp32 -> fp16, swizzled write (two 16-col halves) ----
    const float* xp = X + (size_t)(m0 + arow) * H + k0 + acol0;
#pragma unroll
    for (int h = 0; h < 2; ++h) {
      float4 v0 = ((const float4*)xp)[h * 4 + 0];
      float4 v1 = ((const float4*)xp)[h * 4 + 1];
      float4 v2 = ((const float4*)xp)[h * 4 + 2];
      float4 v3 = ((const float4*)xp)[h * 4 + 3];
      union { s16x8 v; __half2 h2[4]; } u0, u1;
      u0.h2[0] = __floats2half2_rn(v0.x, v0.y);
      u0.h2[1] = __floats2half2_rn(v0.z, v0.w);
      u0.h2[2] = __floats2half2_rn(v1.x, v1.y);
      u0.h2[3] = __floats2half2_rn(v1.z, v1.w);
      u1.h2[0] = __floats2half2_rn(v2.x, v2.y);
      u1.h2[1] = __floats2half2_rn(v2.z, v2.w);
      u1.h2[2] = __floats2half2_rn(v3.x, v3.y);
      u1.h2[3] = __floats2half2_rn(v3.z, v3.w);
      *(s16x8*)&As[arow][(acol0 + h * 16 + 0) ^ asw] = u0.v;
      *(s16x8*)&As[arow][(acol0 + h * 16 + 8) ^ asw] = u1.v;
    }
    // ---- stage B: load q, dequant, swizzled write (two halves) ----
    {
      const int rg = n0g + arow;            // same row/col split as A
      const int* qp = Q + (size_t)rg * H + k0 + acol0;
      const float s = S[rg * G + gidx], z = Z[rg * G + gidx];
#pragma unroll
      for (int h = 0; h < 2; ++h) {
        int4 q0 = ((const int4*)qp)[h * 4 + 0];
        int4 q1 = ((const int4*)qp)[h * 4 + 1];
        int4 q2 = ((const int4*)qp)[h * 4 + 2];
        int4 q3 = ((const int4*)qp)[h * 4 + 3];
        *(s16x8*)&Bs[arow][(acol0 + h * 16 + 0) ^ asw] = dq_compute(q0, q1, s, z);
        *(s16x8*)&Bs[arow][(acol0 + h * 16 + 8) ^ asw] = dq_compute(q2, q3, s, z);
      }
    }
    __syncthreads();
    // ---- MFMA over BK=64 (two K=32 steps) ----
    __builtin_amdgcn_s_setprio(1);
#pragma unroll
    for (int kk = 0; kk < 2; ++kk) {
      const int cbase = (kk * 32 + lq * 8) ^ rsw;
      f16x8 af[4];
#pragma unroll
      for (int i = 0; i < 4; ++i)
        af[i] = *(const f16x8*)&As[wm + i * 16 + l15][cbase];
#pragma unroll
      for (int j = 0; j < 4; ++j) {
        f16x8 bf = *(const f16x8*)&Bs[wn + j * 16 + l15][cbase];
#pragma unroll
        for (int i = 0; i < 4; ++i)
          acc[i][j] = __builtin_amdgcn_mfma_f32_16x16x32_f16(af[i], bf, acc[i][j], 0, 0, 0);
      }
    }
    __builtin_amdgcn_s_setprio(0);
  }
  // ---- epilogue ----
#pragma unroll
  for (int i = 0; i < 4; ++i)
#pragma unroll
    for (int j = 0; j < 4; ++j)
#pragma unroll
      for (int r = 0; r < 4; ++r) {
        const int row = m0 + wm + i * 16 + lq * 4 + r;
        const int col = nb * 128 + wn + j * 16 + l15;
        const size_t idx = (size_t)row * Iw + col;
        if (EPI == 0) {
          Pan[idx] = __float2half(acc[i][j][r]);
        } else {
          float g = __half2float(Pan[idx]);
          float u = acc[i][j][r];
          Pan[idx] = __float2half((g / (1.f + __expf(-g))) * u);
        }
      }
}

// ---------------------------------------------------------------------------
// Down GEMM K-split: out (+)= h_panel @ Wd[:, i0:i0+Iw]^T
// A (h fp16) via global_load_lds (linear dest + swizzled source). 32 KB LDS.
// ---------------------------------------------------------------------------
__global__ __launch_bounds__(256, 4)
void down_kernel(const __half* __restrict__ Hws,
                 const int* __restrict__ Qd,
                 const float* __restrict__ Sd, const float* __restrict__ Zd,
                 float* __restrict__ Out,
                 int i0, int Iw, int beta) {
  constexpr int I = 11008, N = 4096, G = 86;
  const int wg = xcd_swz(blockIdx.x, gridDim.x);
  const int nb = wg & 31;   // nb fastest (32 n-blocks)
  const int mb = wg >> 5;
  const int m0 = mb * 128, n0 = nb * 128;
  const int tid = threadIdx.x;
  const int lane = tid & 63;
  const int wave = tid >> 6;
  const int wm = (wave >> 1) * 64, wn = (wave & 1) * 64;
  const int l15 = lane & 15, lq = lane >> 4;
  const int rsw = (l15 & 7) << 3;
  const int brow = tid >> 3;        // 0..31 (DMA granule coords)
  const int bcol = (tid & 7) * 8;
  const int bswcol = bcol ^ ((brow & 7) << 3);
  const int srow = tid >> 1;        // B dequant: one row, 32 cols
  const int scol0 = (tid & 1) * 32;
  const int ssw = (srow & 7) << 3;

  __shared__ __half As[128][64];
  __shared__ __half Bs[128][64];

  f32x4 acc[4][4];
#pragma unroll
  for (int i = 0; i < 4; ++i)
#pragma unroll
    for (int j = 0; j < 4; ++j) acc[i][j] = {0.f, 0.f, 0.f, 0.f};

  for (int k0 = 0; k0 < Iw; k0 += 64) {
    __syncthreads();
    // ---- stage A: DMA, linear dest + swizzled source ----
#pragma unroll
    for (int c = 0; c < 4; ++c) {
      const int r = c * 32 + brow;
      const __half* src = Hws + (size_t)(m0 + r) * Iw + (k0 + bswcol);
      __half* dst = &As[0][0] + (size_t)(c * 256 + tid) * 8;
      __builtin_amdgcn_global_load_lds((const __attribute__((address_space(1))) void*)src,
                                       (__attribute__((address_space(3))) void*)dst, 16, 0, 0);
    }
    // ---- stage B: Wd dequant, swizzled write ----
    const int gidx = (i0 + k0) >> 7;
    {
      const int rg = n0 + srow;
      const int* qp = Qd + (size_t)rg * I + (i0 + k0 + scol0);
      const float s = Sd[rg * G + gidx], z = Zd[rg * G + gidx];
#pragma unroll
      for (int h = 0; h < 2; ++h) {
        int4 q0 = ((const int4*)qp)[h * 4 + 0];
        int4 q1 = ((const int4*)qp)[h * 4 + 1];
        int4 q2 = ((const int4*)qp)[h * 4 + 2];
        int4 q3 = ((const int4*)qp)[h * 4 + 3];
        *(s16x8*)&Bs[srow][(scol0 + h * 16 + 0) ^ ssw] = dq_compute(q0, q1, s, z);
        *(s16x8*)&Bs[srow][(scol0 + h * 16 + 8) ^ ssw] = dq_compute(q2, q3, s, z);
      }
    }
    __syncthreads();
    __builtin_amdgcn_s_setprio(1);
#pragma unroll
    for (int kk = 0; kk < 2; ++kk) {
      const int cbase = (kk * 32 + lq * 8) ^ rsw;
      f16x8 af[4];
#pragma unroll
      for (int i = 0; i < 4; ++i)
        af[i] = *(const f16x8*)&As[wm + i * 16 + l15][cbase];
#pragma unroll
      for (int j = 0; j < 4; ++j) {
        f16x8 bf = *(const f16x8*)&Bs[wn + j * 16 + l15][cbase];
#pragma unroll
        for (int i = 0; i < 4; ++i)
          acc[i][j] = __builtin_amdgcn_mfma_f32_16x16x32_f16(af[i], bf, acc[i][j], 0, 0, 0);
      }
    }
    __builtin_amdgcn_s_setprio(0);
  }
#pragma unroll
  for (int i = 0; i < 4; ++i)
#pragma unroll
    for (int j = 0; j < 4; ++j)
#pragma unroll
      for (int r = 0; r < 4; ++r) {
        const int row = m0 + wm + i * 16 + lq * 4 + r;
        const int col = n0 + wn + j * 16 + l15;
        const size_t idx = (size_t)row * N + col;
        if (beta) Out[idx] += acc[i][j][r];
        else      Out[idx] = acc[i][j][r];
      }
}

// ---------------------------------------------------------------------------
extern "C" void kernel_launch(void* const* d_in, const int* in_sizes, int n_in,
                              void* d_out, int out_size, void* d_ws, size_t ws_size,
                              hipStream_t stream) {
  const float* x  = (const float*)d_in[0];
  const int* qg   = (const int*)d_in[1];
  const int* qu   = (const int*)d_in[2];
  const int* qd   = (const int*)d_in[3];
  const float* sg = (const float*)d_in[4];
  const float* zg = (const float*)d_in[5];
  const float* su = (const float*)d_in[6];
  const float* zu = (const float*)d_in[7];
  const float* sd = (const float*)d_in[8];
  const float* zd = (const float*)d_in[9];
  float* out = (float*)d_out;

  const int M = 8192, NBTOT = 86;  // I = 86*128

  // I-chunking: single g/h panel [M][nbB*128] fp16 in ws.
  const size_t colblk_bytes = (size_t)M * 128 * 2;  // 2 MiB per 128-col block
  int maxnb = (int)(ws_size / colblk_bytes);
  if (maxnb > NBTOT) maxnb = NBTOT;
  if (maxnb < 1) maxnb = 1;
  const int nch = (NBTOT + maxnb - 1) / maxnb;
  const int base = NBTOT / nch, rem = NBTOT % nch;

  __half* panel = (__half*)d_ws;

  int i0blk = 0;
  for (int c = 0; c < nch; ++c) {
    const int nbB = base + (c < rem ? 1 : 0);
    const int i0 = i0blk * 128;
    const int Iw = nbB * 128;
    qgemm_x_kernel<0><<<nbB * 64, 256, 0, stream>>>(
        x, qg, sg, zg, panel, i0, Iw, nbB);
    qgemm_x_kernel<1><<<nbB * 64, 256, 0, stream>>>(
        x, qu, su, zu, panel, i0, Iw, nbB);
    down_kernel<<<32 * 64, 256, 0, stream>>>(
        panel, qd, sd, zd, out, i0, Iw, c == 0 ? 0 : 1);
    i0blk += nbB;
  }
}

// Round 9
// 4558.885 us; speedup vs baseline: 2.4531x; 2.4531x over previous
//
#include <hip/hip_runtime.h>
#include <hip/hip_fp16.h>

typedef __attribute__((ext_vector_type(8))) short s16x8;
typedef __attribute__((ext_vector_type(8))) _Float16 f16x8;
typedef __attribute__((ext_vector_type(4))) float f32x4;

// ---------------------------------------------------------------------------
// fp32 -> fp16 conversion (vectorized, grid-stride)
// ---------------------------------------------------------------------------
__global__ void cvt_f32_to_f16_kernel(const float* __restrict__ in,
                                      __half* __restrict__ out, long n) {
  long i = (long)blockIdx.x * blockDim.x + threadIdx.x;
  long stride = (long)gridDim.x * blockDim.x;
  const float4* p4 = (const float4*)in;
  for (long j = i; j * 8 < n; j += stride) {
    float4 a = p4[j * 2];
    float4 b = p4[j * 2 + 1];
    union { s16x8 v; __half2 h2[4]; } w;
    w.h2[0] = __floats2half2_rn(a.x, a.y);
    w.h2[1] = __floats2half2_rn(a.z, a.w);
    w.h2[2] = __floats2half2_rn(b.x, b.y);
    w.h2[3] = __floats2half2_rn(b.z, b.w);
    *(s16x8*)(out + j * 8) = w.v;
  }
}

// ---------------------------------------------------------------------------
// Dequant 8 int4-in-int32 -> 8 fp16: f16(64+q)=0x5400|(q<<4); w = b*s-(64+z)*s
// ---------------------------------------------------------------------------
__device__ __forceinline__ s16x8 dq_compute(int4 q0, int4 q1, float s, float z) {
  __half hs = __float2half(s);
  __half2 s2 = __halves2half2(hs, hs);
  __half hc = __float2half(-(64.f + z) * s);
  __half2 c2 = __halves2half2(hc, hc);
  uint32_t b0 = 0x54005400u + ((uint32_t)q0.x << 4) + ((uint32_t)q0.y << 20);
  uint32_t b1 = 0x54005400u + ((uint32_t)q0.z << 4) + ((uint32_t)q0.w << 20);
  uint32_t b2 = 0x54005400u + ((uint32_t)q1.x << 4) + ((uint32_t)q1.y << 20);
  uint32_t b3 = 0x54005400u + ((uint32_t)q1.z << 4) + ((uint32_t)q1.w << 20);
  union { s16x8 v; __half2 h2[4]; } w;
  w.h2[0] = __hfma2(*(__half2*)&b0, s2, c2);
  w.h2[1] = __hfma2(*(__half2*)&b1, s2, c2);
  w.h2[2] = __hfma2(*(__half2*)&b2, s2, c2);
  w.h2[3] = __hfma2(*(__half2*)&b3, s2, c2);
  return w.v;
}

// bijective XCD swizzle (m204): consecutive logical ids land on the same XCD.
__device__ __forceinline__ int xcd_swz(int w0, int nwg) {
  const int q = nwg >> 3, r = nwg & 7;
  const int xcd = w0 & 7, idx = w0 >> 3;
  const int base = (xcd < r) ? xcd * (q + 1) : r * (q + 1) + (xcd - r) * q;
  return base + idx;
}

// ---------------------------------------------------------------------------
// gate/up GEMM, M-chunked, full-I: P = Xh @ Wq^T (dequant inline).
// EPI=0: Pan = fp16(acc).  EPI=1: Pan = silu(Pan) * acc  (in-place h)
// BM=256, BN=128, BK=64. 512 thr (8 waves: 4M x 2N, 64x64 each).
// T14 pipeline: prefetch A/Q(t+1) to regs before MFMA(t); LDS double-buffered.
// ---------------------------------------------------------------------------
template <int EPI>
__global__ __launch_bounds__(512, 2)
void qgemm_x_kernel(const __half* __restrict__ Xh,
                    const int* __restrict__ Q,
                    const float* __restrict__ S, const float* __restrict__ Z,
                    __half* __restrict__ Pan, int mbs) {
  constexpr int H = 4096, I = 11008, G = 32;
  const int wg = xcd_swz(blockIdx.x, gridDim.x);
  const int mb = wg % mbs;          // mb fastest: neighbors share the W panel
  const int nb = wg / mbs;
  const int m0 = mb * 256;
  const int n0 = nb * 128;
  const int tid = threadIdx.x;
  const int lane = tid & 63;
  const int wave = tid >> 6;
  const int wm = (wave >> 1) * 64, wn = (wave & 1) * 64;
  const int l15 = lane & 15, lq = lane >> 4;
  const int rsw = (l15 & 7) << 3;

  __shared__ __half As[2][256][64];   // 64 KB
  __shared__ __half Bs[2][128][64];   // 32 KB

  f32x4 acc[4][4];
#pragma unroll
  for (int i = 0; i < 4; ++i)
#pragma unroll
    for (int j = 0; j < 4; ++j) acc[i][j] = {0.f, 0.f, 0.f, 0.f};

  // staging maps
  const int arow = tid >> 1, acol0 = (tid & 1) * 32, asw = (arow & 7) << 3;
  const int qrow = tid >> 2, qcol0 = (tid & 3) * 16, qsw = (qrow & 7) << 3;
  const __half* aP = Xh + (size_t)(m0 + arow) * H + acol0;
  const int*    qP = Q  + (size_t)(n0 + qrow) * H + qcol0;
  const float*  sP = S + (size_t)(n0 + qrow) * G;
  const float*  zP = Z + (size_t)(n0 + qrow) * G;

  s16x8 apf[4];
  int4  qpf[4];
  float spf, zpf;

  // ---- prologue: load tile 0 to regs, write buf 0 ----
#pragma unroll
  for (int i = 0; i < 4; ++i) apf[i] = ((const s16x8*)aP)[i];
#pragma unroll
  for (int i = 0; i < 4; ++i) qpf[i] = ((const int4*)qP)[i];
  spf = sP[0]; zpf = zP[0];
#pragma unroll
  for (int i = 0; i < 4; ++i) *(s16x8*)&As[0][arow][(acol0 + i * 8) ^ asw] = apf[i];
  *(s16x8*)&Bs[0][qrow][(qcol0 + 0) ^ qsw] = dq_compute(qpf[0], qpf[1], spf, zpf);
  *(s16x8*)&Bs[0][qrow][(qcol0 + 8) ^ qsw] = dq_compute(qpf[2], qpf[3], spf, zpf);
  __syncthreads();

  int p = 0;
  const int nt = H / 64;
  for (int t = 0; t < nt; ++t) {
    if (t + 1 < nt) {
      const int k1 = (t + 1) * 64;
#pragma unroll
      for (int i = 0; i < 4; ++i) apf[i] = ((const s16x8*)(aP + k1))[i];
#pragma unroll
      for (int i = 0; i < 4; ++i) qpf[i] = ((const int4*)(qP + k1))[i];
      spf = sP[k1 >> 7]; zpf = zP[k1 >> 7];
    }
    // ---- MFMA on tile t (loads in flight) ----
    __builtin_amdgcn_s_setprio(1);
#pragma unroll
    for (int kk = 0; kk < 2; ++kk) {
      const int cbase = (kk * 32 + lq * 8) ^ rsw;
      f16x8 af[4];
#pragma unroll
      for (int i = 0; i < 4; ++i)
        af[i] = *(const f16x8*)&As[p][wm + i * 16 + l15][cbase];
#pragma unroll
      for (int j = 0; j < 4; ++j) {
        f16x8 bf = *(const f16x8*)&Bs[p][wn + j * 16 + l15][cbase];
#pragma unroll
        for (int i = 0; i < 4; ++i)
          acc[i][j] = __builtin_amdgcn_mfma_f32_16x16x32_f16(af[i], bf, acc[i][j], 0, 0, 0);
      }
    }
    __builtin_amdgcn_s_setprio(0);
    // ---- write tile t+1 into the other buffer ----
    if (t + 1 < nt) {
#pragma unroll
      for (int i = 0; i < 4; ++i) *(s16x8*)&As[p ^ 1][arow][(acol0 + i * 8) ^ asw] = apf[i];
      *(s16x8*)&Bs[p ^ 1][qrow][(qcol0 + 0) ^ qsw] = dq_compute(qpf[0], qpf[1], spf, zpf);
      *(s16x8*)&Bs[p ^ 1][qrow][(qcol0 + 8) ^ qsw] = dq_compute(qpf[2], qpf[3], spf, zpf);
    }
    __syncthreads();
    p ^= 1;
  }
  // ---- epilogue ----
#pragma unroll
  for (int i = 0; i < 4; ++i)
#pragma unroll
    for (int j = 0; j < 4; ++j)
#pragma unroll
      for (int r = 0; r < 4; ++r) {
        const int row = m0 + wm + i * 16 + lq * 4 + r;
        const int col = n0 + wn + j * 16 + l15;
        const size_t idx = (size_t)row * I + col;
        if (EPI == 0) {
          Pan[idx] = __float2half(acc[i][j][r]);
        } else {
          float g = __half2float(Pan[idx]);
          float u = acc[i][j][r];
          Pan[idx] = __float2half((g / (1.f + __expf(-g))) * u);
        }
      }
}

// ---------------------------------------------------------------------------
// Down GEMM, M-chunked, full-K: out = h @ Wd^T. Same pipeline. K=11008.
// ---------------------------------------------------------------------------
__global__ __launch_bounds__(512, 2)
void down_kernel(const __half* __restrict__ Hws,
                 const int* __restrict__ Qd,
                 const float* __restrict__ Sd, const float* __restrict__ Zd,
                 float* __restrict__ Out, int mbs) {
  constexpr int K = 11008, N = 4096, G = 86;
  const int wg = xcd_swz(blockIdx.x, gridDim.x);
  const int mb = wg % mbs;
  const int nb = wg / mbs;
  const int m0 = mb * 256, n0 = nb * 128;
  const int tid = threadIdx.x;
  const int lane = tid & 63;
  const int wave = tid >> 6;
  const int wm = (wave >> 1) * 64, wn = (wave & 1) * 64;
  const int l15 = lane & 15, lq = lane >> 4;
  const int rsw = (l15 & 7) << 3;

  __shared__ __half As[2][256][64];
  __shared__ __half Bs[2][128][64];

  f32x4 acc[4][4];
#pragma unroll
  for (int i = 0; i < 4; ++i)
#pragma unroll
    for (int j = 0; j < 4; ++j) acc[i][j] = {0.f, 0.f, 0.f, 0.f};

  const int arow = tid >> 1, acol0 = (tid & 1) * 32, asw = (arow & 7) << 3;
  const int qrow = tid >> 2, qcol0 = (tid & 3) * 16, qsw = (qrow & 7) << 3;
  const __half* aP = Hws + (size_t)(m0 + arow) * K + acol0;
  const int*    qP = Qd  + (size_t)(n0 + qrow) * K + qcol0;
  const float*  sP = Sd + (size_t)(n0 + qrow) * G;
  const float*  zP = Zd + (size_t)(n0 + qrow) * G;

  s16x8 apf[4];
  int4  qpf[4];
  float spf, zpf;

#pragma unroll
  for (int i = 0; i < 4; ++i) apf[i] = ((const s16x8*)aP)[i];
#pragma unroll
  for (int i = 0; i < 4; ++i) qpf[i] = ((const int4*)qP)[i];
  spf = sP[0]; zpf = zP[0];
#pragma unroll
  for (int i = 0; i < 4; ++i) *(s16x8*)&As[0][arow][(acol0 + i * 8) ^ asw] = apf[i];
  *(s16x8*)&Bs[0][qrow][(qcol0 + 0) ^ qsw] = dq_compute(qpf[0], qpf[1], spf, zpf);
  *(s16x8*)&Bs[0][qrow][(qcol0 + 8) ^ qsw] = dq_compute(qpf[2], qpf[3], spf, zpf);
  __syncthreads();

  int p = 0;
  const int nt = K / 64;
  for (int t = 0; t < nt; ++t) {
    if (t + 1 < nt) {
      const int k1 = (t + 1) * 64;
#pragma unroll
      for (int i = 0; i < 4; ++i) apf[i] = ((const s16x8*)(aP + k1))[i];
#pragma unroll
      for (int i = 0; i < 4; ++i) qpf[i] = ((const int4*)(qP + k1))[i];
      spf = sP[k1 >> 7]; zpf = zP[k1 >> 7];
    }
    __builtin_amdgcn_s_setprio(1);
#pragma unroll
    for (int kk = 0; kk < 2; ++kk) {
      const int cbase = (kk * 32 + lq * 8) ^ rsw;
      f16x8 af[4];
#pragma unroll
      for (int i = 0; i < 4; ++i)
        af[i] = *(const f16x8*)&As[p][wm + i * 16 + l15][cbase];
#pragma unroll
      for (int j = 0; j < 4; ++j) {
        f16x8 bf = *(const f16x8*)&Bs[p][wn + j * 16 + l15][cbase];
#pragma unroll
        for (int i = 0; i < 4; ++i)
          acc[i][j] = __builtin_amdgcn_mfma_f32_16x16x32_f16(af[i], bf, acc[i][j], 0, 0, 0);
      }
    }
    __builtin_amdgcn_s_setprio(0);
    if (t + 1 < nt) {
#pragma unroll
      for (int i = 0; i < 4; ++i) *(s16x8*)&As[p ^ 1][arow][(acol0 + i * 8) ^ asw] = apf[i];
      *(s16x8*)&Bs[p ^ 1][qrow][(qcol0 + 0) ^ qsw] = dq_compute(qpf[0], qpf[1], spf, zpf);
      *(s16x8*)&Bs[p ^ 1][qrow][(qcol0 + 8) ^ qsw] = dq_compute(qpf[2], qpf[3], spf, zpf);
    }
    __syncthreads();
    p ^= 1;
  }
#pragma unroll
  for (int i = 0; i < 4; ++i)
#pragma unroll
    for (int j = 0; j < 4; ++j)
#pragma unroll
      for (int r = 0; r < 4; ++r) {
        const int row = m0 + wm + i * 16 + lq * 4 + r;
        const int col = n0 + wn + j * 16 + l15;
        Out[(size_t)row * N + col] = acc[i][j][r];
      }
}

// ---------------------------------------------------------------------------
extern "C" void kernel_launch(void* const* d_in, const int* in_sizes, int n_in,
                              void* d_out, int out_size, void* d_ws, size_t ws_size,
                              hipStream_t stream) {
  const float* x  = (const float*)d_in[0];
  const int* qg   = (const int*)d_in[1];
  const int* qu   = (const int*)d_in[2];
  const int* qd   = (const int*)d_in[3];
  const float* sg = (const float*)d_in[4];
  const float* zg = (const float*)d_in[5];
  const float* su = (const float*)d_in[6];
  const float* zu = (const float*)d_in[7];
  const float* sd = (const float*)d_in[8];
  const float* zd = (const float*)d_in[9];
  float* out = (float*)d_out;

  const int M = 8192, H = 4096, I = 11008;

  // M-chunking: x fp16 chunk + h panel chunk in ws. Mc multiple of 256.
  const size_t per_row = (size_t)(H + I) * 2;
  long mc = (long)(ws_size / per_row);
  mc &= ~255L;
  if (mc > M) mc = M;
  if (mc < 256) mc = 256;
  const int Mc = (int)mc;

  __half* wsx = (__half*)d_ws;
  __half* wsh = (__half*)((char*)d_ws + (size_t)Mc * H * 2);

  for (int mbase = 0; mbase < M; mbase += Mc) {
    const int rows = (M - mbase < Mc) ? (M - mbase) : Mc;
    const int mbs = rows / 256;
    cvt_f32_to_f16_kernel<<<1024, 256, 0, stream>>>(
        x + (size_t)mbase * H, wsx, (long)rows * H);
    qgemm_x_kernel<0><<<mbs * (I / 128), 512, 0, stream>>>(
        wsx, qg, sg, zg, wsh, mbs);
    qgemm_x_kernel<1><<<mbs * (I / 128), 512, 0, stream>>>(
        wsx, qu, su, zu, wsh, mbs);
    down_kernel<<<mbs * (H / 128), 512, 0, stream>>>(
        wsh, qd, sd, zd, out + (size_t)mbase * H, mbs);
  }
}